// Round 12
// baseline (510.556 us; speedup 1.0000x reference)
//
#include <hip/hip_runtime.h>

typedef _Float16 f16x8 __attribute__((ext_vector_type(8)));
typedef float f32x4 __attribute__((ext_vector_type(4)));
typedef unsigned short u16;
typedef u16 u16x4 __attribute__((ext_vector_type(4)));
typedef u16 u16x8 __attribute__((ext_vector_type(8)));

#define NBATCH 16
#define NSEQ   2048
#define NHID   1024
#define MALL   (NBATCH * NSEQ)   // 32768

__device__ __forceinline__ u16 f16_rne(float x) {
    _Float16 h = (_Float16)x;
    return __builtin_bit_cast(u16, h);
}
__device__ __forceinline__ float fast_tanh(float x) {
    float e = __expf(2.0f * x);
    return 1.0f - 2.0f / (e + 1.0f);
}

#define GLOAD16(g, l) __builtin_amdgcn_global_load_lds(                         \
    (const __attribute__((address_space(1))) unsigned int*)(g),                 \
    (__attribute__((address_space(3))) unsigned int*)(l), 16, 0, 0)

// ===========================================================================
// 256x256 BK=64 f16 GEMM core — 8-phase (4 phases/K-tile), R10/R11-proven.
// ===========================================================================

#define NOPS ((void)0)
#define VMW4 asm volatile("s_waitcnt vmcnt(4)" ::: "memory");
#define VMW0 asm volatile("s_waitcnt vmcnt(0)" ::: "memory");

#define MMPH(MH, NH)                                                           \
    MM(acc[MH][NH][0][0], 0, (NH)*2+0); MM(acc[MH][NH][0][1], 0, (NH)*2+1);    \
    MM(acc[MH][NH][1][0], 1, (NH)*2+0); MM(acc[MH][NH][1][1], 1, (NH)*2+1);    \
    MM(acc[MH][NH][2][0], 2, (NH)*2+0); MM(acc[MH][NH][2][1], 2, (NH)*2+1);    \
    MM(acc[MH][NH][3][0], 3, (NH)*2+0); MM(acc[MH][NH][3][1], 3, (NH)*2+1);    \
    MM(acc[MH][NH][0][0], 4, (NH)*2+4); MM(acc[MH][NH][0][1], 4, (NH)*2+5);    \
    MM(acc[MH][NH][1][0], 5, (NH)*2+4); MM(acc[MH][NH][1][1], 5, (NH)*2+5);    \
    MM(acc[MH][NH][2][0], 6, (NH)*2+4); MM(acc[MH][NH][2][1], 6, (NH)*2+5);    \
    MM(acc[MH][NH][3][0], 7, (NH)*2+4); MM(acc[MH][NH][3][1], 7, (NH)*2+5);

#define PH_SYNC                                                                \
    __builtin_amdgcn_s_barrier();                                              \
    asm volatile("s_waitcnt lgkmcnt(0)" ::: "memory");                         \
    __builtin_amdgcn_sched_barrier(0);

#define TILE8(C, S1, S2, S3, S4, W) {                                          \
    /* P1: (0,0) */                                                            \
    LDA(0,C,0,0); LDA(1,C,0,0); LDA(2,C,0,0); LDA(3,C,0,0);                    \
    LDA(4,C,0,1); LDA(5,C,0,1); LDA(6,C,0,1); LDA(7,C,0,1);                    \
    LDB(0,C,0,0); LDB(1,C,0,0); LDB(4,C,0,1); LDB(5,C,0,1);                    \
    S1;                                                                        \
    PH_SYNC                                                                    \
    __builtin_amdgcn_s_setprio(1); MMPH(0,0) __builtin_amdgcn_s_setprio(0);    \
    __builtin_amdgcn_s_barrier();                                              \
    /* P2: (0,1) */                                                            \
    LDB(2,C,1,0); LDB(3,C,1,0); LDB(6,C,1,1); LDB(7,C,1,1);                    \
    S2;                                                                        \
    PH_SYNC                                                                    \
    __builtin_amdgcn_s_setprio(1); MMPH(0,1) __builtin_amdgcn_s_setprio(0);    \
    __builtin_amdgcn_s_barrier();                                              \
    /* P3: (1,0) */                                                            \
    LDA(0,C,1,0); LDA(1,C,1,0); LDA(2,C,1,0); LDA(3,C,1,0);                    \
    LDA(4,C,1,1); LDA(5,C,1,1); LDA(6,C,1,1); LDA(7,C,1,1);                    \
    S3;                                                                        \
    PH_SYNC                                                                    \
    __builtin_amdgcn_s_setprio(1); MMPH(1,0) __builtin_amdgcn_s_setprio(0);    \
    __builtin_amdgcn_s_barrier();                                              \
    /* P4: (1,1) */                                                            \
    S4;                                                                        \
    PH_SYNC                                                                    \
    __builtin_amdgcn_s_setprio(1); MMPH(1,1) __builtin_amdgcn_s_setprio(0);    \
    W;                                                                         \
    __builtin_amdgcn_s_barrier();                                              \
}

template<int AST, int BST>
__device__ __forceinline__ void gemm_core64(
    const u16* __restrict__ Ap, int Arow0,
    const u16* __restrict__ Bp, int Brow0,
    int nt, u16* lds, f32x4 (&acc)[2][2][4][2])
{
    int tid = threadIdx.x;
    int l = tid & 63, w = tid >> 6;            // lane, wave 0..7
    int wr = w >> 2, wc = w & 3;               // 2M x 4N wave grid
    int fr = l & 15, sg = l >> 4;

    f16x8 ah[8], bh[8];

    auto LDA = [&](int i, int C, int MH, int KH) {
        int rb = MH * 128 + wr * 64 + (i & 3) * 16 + fr;
        int sl = ((KH * 4 + sg) ^ (rb & 7)) * 8;
        ah[i] = *(const f16x8*)&lds[C * 32768 + rb * 64 + sl];
    };
    auto LDB = [&](int j, int C, int NH, int KH) {
        int rb = NH * 128 + wc * 32 + (j & 1) * 16 + fr;
        int sl = ((KH * 4 + sg) ^ (rb & 7)) * 8;
        bh[j] = *(const f16x8*)&lds[C * 32768 + 16384 + rb * 64 + sl];
    };
    auto MM = [&](f32x4& d, int i, int j) {
        d = __builtin_amdgcn_mfma_f32_16x16x32_f16(ah[i], bh[j], d, 0, 0, 0);
    };
    auto STA = [&](int C, int H, int T) {
        int rg = Arow0 + H * 128 + w * 8 + (l >> 3);
        const u16* s = Ap + (size_t)rg * AST + (size_t)T * 64
                       + ((l & 7) ^ (rg & 7)) * 8;
        u16* d = &lds[C * 32768 + (H * 128 + w * 8) * 64];
        GLOAD16(s, d);
        GLOAD16(s + (size_t)64 * AST, d + 64 * 64);
    };
    auto STB = [&](int C, int H, int T) {
        int rg = Brow0 + H * 128 + w * 8 + (l >> 3);
        const u16* s = Bp + (size_t)rg * BST + (size_t)T * 64
                       + ((l & 7) ^ (rg & 7)) * 8;
        u16* d = &lds[C * 32768 + 16384 + (H * 128 + w * 8) * 64];
        GLOAD16(s, d);
        GLOAD16(s + (size_t)64 * BST, d + 64 * 64);
    };

    // prologue: tile0 all 4 halves (8 loads) + tile1 H0s (4 loads)
    STA(0, 0, 0); STA(0, 1, 0); STB(0, 0, 0); STB(0, 1, 0);
    STA(1, 0, 1); STB(1, 0, 1);
    VMW4                                       // tile0 landed; tile1-H0 in flight
    __builtin_amdgcn_s_barrier();

    for (int u = 0; u + 2 < nt; u += 2) {
        TILE8(0, STA(1,1,u+1), STB(1,1,u+1), STA(0,0,u+2), STB(0,0,u+2), VMW4)
        TILE8(1, STA(0,1,u+2), STB(0,1,u+2), STA(1,0,u+3), STB(1,0,u+3), VMW4)
    }
    // epilogue: tile nt-2 (stage nt-1 H1, drain), tile nt-1 (pure compute)
    TILE8(0, STA(1,1,nt-1), STB(1,1,nt-1), NOPS, NOPS, VMW0)
    TILE8(1, NOPS, NOPS, NOPS, NOPS, NOPS)
}

// ---------------------------------------------------------------------------
// P2 (merged prep): y<16: x -> x_f16 + xT.  y==16: w -> wT (f16, *64).
// ---------------------------------------------------------------------------
__global__ __launch_bounds__(256) void prep_kernel(
    const float* __restrict__ x, u16* __restrict__ xT,
    u16* __restrict__ x_f16,
    const float* __restrict__ wa, const float* __restrict__ qu,
    u16* __restrict__ wT)
{
    int tid = threadIdx.x;
    if (blockIdx.y == 16) {
        // wprep: 512 blocks (x:0..31, z:0..15) x 256 thr x 8 elems = 1M
        int bid = blockIdx.z * 32 + blockIdx.x;
        #pragma unroll
        for (int i = 0; i < 8; i++) {
            int idx = (bid * 8 + i) * 256 + tid;     // 0..1M-1
            int h = idx >> 10, n = idx & 1023;
            wT[(size_t)n * 1024 + h]          = f16_rne(wa[idx] * 64.0f);
            wT[(size_t)(1024 + n) * 1024 + h] = f16_rne(qu[idx] * 64.0f);
        }
        return;
    }
    __shared__ u16 tile[64][68];
    int b = blockIdx.z;
    int t0 = blockIdx.x * 64;
    int h0 = blockIdx.y * 64;
    const float* xb = x + ((size_t)b * NSEQ + t0) * NHID + h0;
    int tl = tid >> 4;               // 0..15
    int hl = (tid & 15) * 4;         // 0..60
    #pragma unroll
    for (int i = 0; i < 4; i++) {
        int r = i * 16 + tl;
        float4 v = *(const float4*)&xb[(size_t)r * NHID + hl];
        u16x4 hv;
        hv[0] = f16_rne(v.x); hv[1] = f16_rne(v.y);
        hv[2] = f16_rne(v.z); hv[3] = f16_rne(v.w);
        *(u16x4*)&tile[r][hl] = hv;
        *(u16x4*)&x_f16[((size_t)(b * NSEQ) + t0 + r) * NHID + h0 + hl] = hv;
    }
    __syncthreads();
    u16* xTb = xT + ((size_t)b * NHID + h0) * NSEQ + t0;
    int hl2 = tid >> 4;              // 0..15
    int tl2 = (tid & 15) * 4;        // 0..60
    #pragma unroll
    for (int i = 0; i < 4; i++) {
        int hh = i * 16 + hl2;
        u16x4 o;
        o[0] = tile[tl2 + 0][hh]; o[1] = tile[tl2 + 1][hh];
        o[2] = tile[tl2 + 2][hh]; o[3] = tile[tl2 + 3][hh];
        *(u16x4*)&xTb[(size_t)hh * NSEQ + tl2] = o;
    }
}

// ---------------------------------------------------------------------------
// K1: key = tanh(x @ w_a), q = x @ query   (plain f16, B pre-scaled by 64)
// ---------------------------------------------------------------------------
__global__ __launch_bounds__(512, 2) void k1_gemm(
    const u16* __restrict__ x_f16, const u16* __restrict__ wT,
    u16* __restrict__ k_f16, u16* __restrict__ q_f16)
{
    extern __shared__ u16 lds[];
    int wg = blockIdx.x;                       // 1024 blocks
    int nid = (wg & 7) * 128 + (wg >> 3);      // XCD-chunked
    int n0 = (nid & 7) * 256;
    int m0 = (nid >> 3) * 256;
    bool is_key = (n0 < 1024);

    f32x4 acc[2][2][4][2] = {};
    gemm_core64<1024, 1024>(x_f16, m0, wT, n0, 16, lds, acc);

    int tid = threadIdx.x;
    int l = tid & 63, w = tid >> 6;
    int wr = w >> 2, wc = w & 3;
    int fr = l & 15, fq = l >> 4;
    int nb = is_key ? n0 : (n0 - 1024);
    u16* outp = is_key ? k_f16 : q_f16;
    #pragma unroll
    for (int mh = 0; mh < 2; mh++)
    #pragma unroll
    for (int nh = 0; nh < 2; nh++)
    #pragma unroll
    for (int m = 0; m < 4; m++)
    #pragma unroll
    for (int n = 0; n < 2; n++)
    #pragma unroll
    for (int j = 0; j < 4; j++) {
        int grow = m0 + mh * 128 + wr * 64 + m * 16 + fq * 4 + j;
        int c    = nb + nh * 128 + wc * 32 + n * 16 + fr;
        float v = acc[mh][nh][m][n][j] * 0.015625f;   // /64 (B was scaled)
        outp[(size_t)grow * 1024 + c] = f16_rne(is_key ? fast_tanh(v) : v);
    }
}

// ---------------------------------------------------------------------------
// K2: logits = q . key  (causal 256x256 tiles) + upper-triangle zero-fill
// ---------------------------------------------------------------------------
__global__ __launch_bounds__(512, 2) void k2_logits(
    const u16* __restrict__ q_f16, const u16* __restrict__ k_f16,
    float* __restrict__ dmat)
{
    extern __shared__ u16 lds[];
    int wg = blockIdx.x;                       // 1024 = 576 compute + 448 zfill
    int tid = threadIdx.x;

    if (wg >= 576) {
        // zero-fill strictly-upper 256x256 tiles (tt > st)
        int z = wg - 576;                      // 0..447
        int b = z / 28;
        int lin = z - b * 28;
        int tt = 1;
        while ((tt + 1) * tt / 2 <= lin) tt++;
        int st = lin - tt * (tt - 1) / 2;      // st < tt
        float* db = dmat + (size_t)b * NSEQ * NSEQ;
        size_t base = (size_t)(st * 256) * NSEQ + tt * 256;
        float4 zz = make_float4(0.f, 0.f, 0.f, 0.f);
        #pragma unroll
        for (int i = 0; i < 32; i++) {
            int e = i * 512 + tid;
            int row = e >> 6, c4 = e & 63;
            *(float4*)&db[base + (size_t)row * NSEQ + c4 * 4] = zz;
        }
        return;
    }

    int nid = (wg & 7) * 72 + (wg >> 3);
    int b = nid / 36;
    int lin = nid - b * 36;
    int st = 0;
    while ((st + 1) * (st + 2) / 2 <= lin) st++;
    int tt = lin - st * (st + 1) / 2;
    int s0 = st * 256, t0 = tt * 256;
    int base = b * NSEQ;

    f32x4 acc[2][2][4][2] = {};
    gemm_core64<1024, 1024>(q_f16, base + s0, k_f16, base + t0, 16, lds, acc);

    float* db = dmat + (size_t)b * NSEQ * NSEQ;
    int l = tid & 63, w = tid >> 6;
    int wr = w >> 2, wc = w & 3;
    int fr = l & 15, fq = l >> 4;
    #pragma unroll
    for (int mh = 0; mh < 2; mh++)
    #pragma unroll
    for (int nh = 0; nh < 2; nh++)
    #pragma unroll
    for (int m = 0; m < 4; m++)
    #pragma unroll
    for (int n = 0; n < 2; n++)
    #pragma unroll
    for (int j = 0; j < 4; j++) {
        int s = s0 + mh * 128 + wr * 64 + m * 16 + fq * 4 + j;
        int t = t0 + nh * 128 + wc * 32 + n * 16 + fr;
        db[(size_t)s * NSEQ + t] = (t <= s) ? acc[mh][nh][m][n][j] : 0.0f;
    }
}

// ---------------------------------------------------------------------------
// K3: causal softmax, 2 rows per 512-thread block (waves 0-3 row0, 4-7 row1).
// dmat writes only t0<=s (upper zeros from K2); d_f16 band 256-aligned.
// ---------------------------------------------------------------------------
__global__ __launch_bounds__(512) void k3_softmax(
    float* __restrict__ dmat, u16* __restrict__ d_f16)
{
    __shared__ float redm[8];
    __shared__ float reds[8];
    int half = threadIdx.x >> 8;        // 0 or 1
    int tid = threadIdx.x & 255;
    int rowid = blockIdx.x * 2 + half;  // b*2048 + s
    int s = rowid & (NSEQ - 1);
    float* row = dmat + (size_t)rowid * NSEQ;
    int lane = tid & 63, w = threadIdx.x >> 6;   // w: 0-3 row0, 4-7 row1
    int t0 = tid * 8;

    float v[8];
    if (t0 <= s) {
        float4 a = *(const float4*)&row[t0];
        float4 c = *(const float4*)&row[t0 + 4];
        v[0] = a.x; v[1] = a.y; v[2] = a.z; v[3] = a.w;
        v[4] = c.x; v[5] = c.y; v[6] = c.z; v[7] = c.w;
        #pragma unroll
        for (int i = 0; i < 8; i++) if (t0 + i > s) v[i] = -INFINITY;
    } else {
        #pragma unroll
        for (int i = 0; i < 8; i++) v[i] = -INFINITY;
    }

    float m = -INFINITY;
    #pragma unroll
    for (int i = 0; i < 8; i++) m = fmaxf(m, v[i]);
    #pragma unroll
    for (int off = 32; off > 0; off >>= 1) m = fmaxf(m, __shfl_xor(m, off));
    if (lane == 0) redm[w] = m;
    __syncthreads();
    {
        int wb = half * 4;
        m = fmaxf(fmaxf(redm[wb], redm[wb + 1]), fmaxf(redm[wb + 2], redm[wb + 3]));
    }

    float sum = 0.f;
    float ev[8];
    #pragma unroll
    for (int i = 0; i < 8; i++) {
        ev[i] = (t0 + i <= s) ? __expf(v[i] - m) : 0.f;
        sum += ev[i];
    }
    #pragma unroll
    for (int off = 32; off > 0; off >>= 1) sum += __shfl_xor(sum, off);
    if (lane == 0) reds[w] = sum;
    __syncthreads();
    {
        int wb = half * 4;
        sum = reds[wb] + reds[wb + 1] + reds[wb + 2] + reds[wb + 3];
    }
    float inv = 1.0f / sum;

    float4 o0, o1;
    o0.x = ev[0] * inv; o0.y = ev[1] * inv; o0.z = ev[2] * inv; o0.w = ev[3] * inv;
    o1.x = ev[4] * inv; o1.y = ev[5] * inv; o1.z = ev[6] * inv; o1.w = ev[7] * inv;
    if (t0 <= s) {
        *(float4*)&row[t0] = o0;
        *(float4*)&row[t0 + 4] = o1;
    }
    if (t0 < (((s >> 8) + 1) << 8)) {
        u16x8 bv;
        bv[0] = f16_rne(o0.x); bv[1] = f16_rne(o0.y); bv[2] = f16_rne(o0.z); bv[3] = f16_rne(o0.w);
        bv[4] = f16_rne(o1.x); bv[5] = f16_rne(o1.y); bv[6] = f16_rne(o1.z); bv[7] = f16_rne(o1.w);
        *(u16x8*)&d_f16[(size_t)rowid * NSEQ + t0] = bv;
    }
}

// ---------------------------------------------------------------------------
// K4: a = d @ x  (256x256 8-phase core, K truncated at 256-aligned diagonal).
// LPT: heavy s-tiles first; ntile fastest; no XCD chunking (R8 lesson).
// ---------------------------------------------------------------------------
__global__ __launch_bounds__(512, 2) void k4_av(
    const u16* __restrict__ d_f16,
    const u16* __restrict__ xT,
    float* __restrict__ aout)
{
    extern __shared__ u16 lds[];
    int wg = blockIdx.x;                  // 512 = 8 st * 16 b * 4 nt
    int st = 7 - (wg >> 6);               // heavy first (st=7 -> nt=32)
    int rem = wg & 63;
    int b = rem >> 2;
    int ntile = rem & 3;
    int s0 = st * 256;
    int n0 = ntile * 256;
    int nt = 4 * (st + 1);                // covers t < 256*(st+1) = d_f16 band

    f32x4 acc[2][2][4][2] = {};
    gemm_core64<2048, 2048>(d_f16, b * 2048 + s0, xT, b * 1024 + n0, nt, lds, acc);

    float* ab = aout + (size_t)b * NSEQ * NHID;
    int tid = threadIdx.x;
    int l = tid & 63, w = tid >> 6;
    int wr = w >> 2, wc = w & 3;
    int fr = l & 15, fq = l >> 4;
    #pragma unroll
    for (int mh = 0; mh < 2; mh++)
    #pragma unroll
    for (int nh = 0; nh < 2; nh++)
    #pragma unroll
    for (int m = 0; m < 4; m++)
    #pragma unroll
    for (int n = 0; n < 2; n++)
    #pragma unroll
    for (int j = 0; j < 4; j++) {
        int s = s0 + mh * 128 + wr * 64 + m * 16 + fq * 4 + j;
        int c = n0 + nh * 128 + wc * 32 + n * 16 + fr;
        ab[(size_t)s * NHID + c] = acc[mh][nh][m][n][j];
    }
}

// ---------------------------------------------------------------------------
extern "C" void kernel_launch(void* const* d_in, const int* in_sizes, int n_in,
                              void* d_out, int out_size, void* d_ws, size_t ws_size,
                              hipStream_t stream)
{
    const float* x     = (const float*)d_in[0];
    const float* w_a   = (const float*)d_in[1];
    const float* query = (const float*)d_in[2];

    float* aout = (float*)d_out;                         // [16][2048][1024]
    float* dmat = aout + (size_t)NBATCH * NSEQ * NHID;   // [16][2048][2048]

    char* p = (char*)d_ws;
    u16* q_f16  = (u16*)p; p += (size_t)MALL * 1024 * 2;    // 64MB
    u16* x_f16  = (u16*)p; p += (size_t)MALL * 1024 * 2;    // 64MB (dead after K1)
    u16* k_f16  = (u16*)p; p += (size_t)MALL * 1024 * 2;    // 64MB (dead after K2)
    u16* d_f16  = x_f16;                                    // alias x_f16+k_f16 (128MB)
    u16* xT     = (u16*)p; p += (size_t)MALL * 1024 * 2;    // 64MB
    u16* wT     = (u16*)p; p += (size_t)2048 * 1024 * 2;    // 4MB
    (void)ws_size; (void)in_sizes; (void)n_in; (void)out_size;

    hipFuncSetAttribute((const void*)k1_gemm,
                        hipFuncAttributeMaxDynamicSharedMemorySize, 131072);
    hipFuncSetAttribute((const void*)k2_logits,
                        hipFuncAttributeMaxDynamicSharedMemorySize, 131072);
    hipFuncSetAttribute((const void*)k4_av,
                        hipFuncAttributeMaxDynamicSharedMemorySize, 131072);

    prep_kernel<<<dim3(32, 17, 16), 256, 0, stream>>>(x, xT, x_f16, w_a, query, wT);
    k1_gemm<<<dim3(1024), 512, 131072, stream>>>(x_f16, wT, k_f16, q_f16);
    k2_logits<<<dim3(1024), 512, 131072, stream>>>(q_f16, k_f16, dmat);
    k3_softmax<<<dim3(16384), 512, 0, stream>>>(dmat, d_f16);
    k4_av<<<dim3(512), 512, 131072, stream>>>(d_f16, xT, aout);
}

// Round 13
// 501.907 us; speedup vs baseline: 1.0172x; 1.0172x over previous
//
#include <hip/hip_runtime.h>

typedef _Float16 f16x8 __attribute__((ext_vector_type(8)));
typedef float f32x4 __attribute__((ext_vector_type(4)));
typedef unsigned short u16;
typedef u16 u16x4 __attribute__((ext_vector_type(4)));
typedef u16 u16x8 __attribute__((ext_vector_type(8)));

#define NBATCH 16
#define NSEQ   2048
#define NHID   1024
#define MALL   (NBATCH * NSEQ)   // 32768

__device__ __forceinline__ u16 f16_rne(float x) {
    _Float16 h = (_Float16)x;
    return __builtin_bit_cast(u16, h);
}
__device__ __forceinline__ float fast_tanh(float x) {
    float e = __expf(2.0f * x);
    return 1.0f - 2.0f / (e + 1.0f);
}

#define GLOAD16(g, l) __builtin_amdgcn_global_load_lds(                         \
    (const __attribute__((address_space(1))) unsigned int*)(g),                 \
    (__attribute__((address_space(3))) unsigned int*)(l), 16, 0, 0)

// ===========================================================================
// 256x256 BK=64 f16 GEMM core — 8-phase (4 phases/K-tile), R10/R11-proven.
// ===========================================================================

#define NOPS ((void)0)
#define VMW4 asm volatile("s_waitcnt vmcnt(4)" ::: "memory");
#define VMW0 asm volatile("s_waitcnt vmcnt(0)" ::: "memory");

#define MMPH(MH, NH)                                                           \
    MM(acc[MH][NH][0][0], 0, (NH)*2+0); MM(acc[MH][NH][0][1], 0, (NH)*2+1);    \
    MM(acc[MH][NH][1][0], 1, (NH)*2+0); MM(acc[MH][NH][1][1], 1, (NH)*2+1);    \
    MM(acc[MH][NH][2][0], 2, (NH)*2+0); MM(acc[MH][NH][2][1], 2, (NH)*2+1);    \
    MM(acc[MH][NH][3][0], 3, (NH)*2+0); MM(acc[MH][NH][3][1], 3, (NH)*2+1);    \
    MM(acc[MH][NH][0][0], 4, (NH)*2+4); MM(acc[MH][NH][0][1], 4, (NH)*2+5);    \
    MM(acc[MH][NH][1][0], 5, (NH)*2+4); MM(acc[MH][NH][1][1], 5, (NH)*2+5);    \
    MM(acc[MH][NH][2][0], 6, (NH)*2+4); MM(acc[MH][NH][2][1], 6, (NH)*2+5);    \
    MM(acc[MH][NH][3][0], 7, (NH)*2+4); MM(acc[MH][NH][3][1], 7, (NH)*2+5);

#define PH_SYNC                                                                \
    __builtin_amdgcn_s_barrier();                                              \
    asm volatile("s_waitcnt lgkmcnt(0)" ::: "memory");                         \
    __builtin_amdgcn_sched_barrier(0);

#define TILE8(C, S1, S2, S3, S4, W) {                                          \
    /* P1: (0,0) */                                                            \
    LDA(0,C,0,0); LDA(1,C,0,0); LDA(2,C,0,0); LDA(3,C,0,0);                    \
    LDA(4,C,0,1); LDA(5,C,0,1); LDA(6,C,0,1); LDA(7,C,0,1);                    \
    LDB(0,C,0,0); LDB(1,C,0,0); LDB(4,C,0,1); LDB(5,C,0,1);                    \
    S1;                                                                        \
    PH_SYNC                                                                    \
    __builtin_amdgcn_s_setprio(1); MMPH(0,0) __builtin_amdgcn_s_setprio(0);    \
    __builtin_amdgcn_s_barrier();                                              \
    /* P2: (0,1) */                                                            \
    LDB(2,C,1,0); LDB(3,C,1,0); LDB(6,C,1,1); LDB(7,C,1,1);                    \
    S2;                                                                        \
    PH_SYNC                                                                    \
    __builtin_amdgcn_s_setprio(1); MMPH(0,1) __builtin_amdgcn_s_setprio(0);    \
    __builtin_amdgcn_s_barrier();                                              \
    /* P3: (1,0) */                                                            \
    LDA(0,C,1,0); LDA(1,C,1,0); LDA(2,C,1,0); LDA(3,C,1,0);                    \
    LDA(4,C,1,1); LDA(5,C,1,1); LDA(6,C,1,1); LDA(7,C,1,1);                    \
    S3;                                                                        \
    PH_SYNC                                                                    \
    __builtin_amdgcn_s_setprio(1); MMPH(1,0) __builtin_amdgcn_s_setprio(0);    \
    __builtin_amdgcn_s_barrier();                                              \
    /* P4: (1,1) */                                                            \
    S4;                                                                        \
    PH_SYNC                                                                    \
    __builtin_amdgcn_s_setprio(1); MMPH(1,1) __builtin_amdgcn_s_setprio(0);    \
    W;                                                                         \
    __builtin_amdgcn_s_barrier();                                              \
}

template<int AST, int BST>
__device__ __forceinline__ void gemm_core64(
    const u16* __restrict__ Ap, int Arow0,
    const u16* __restrict__ Bp, int Brow0,
    int nt, u16* lds, f32x4 (&acc)[2][2][4][2])
{
    int tid = threadIdx.x;
    int l = tid & 63, w = tid >> 6;            // lane, wave 0..7
    int wr = w >> 2, wc = w & 3;               // 2M x 4N wave grid
    int fr = l & 15, sg = l >> 4;

    f16x8 ah[8], bh[8];

    auto LDA = [&](int i, int C, int MH, int KH) {
        int rb = MH * 128 + wr * 64 + (i & 3) * 16 + fr;
        int sl = ((KH * 4 + sg) ^ (rb & 7)) * 8;
        ah[i] = *(const f16x8*)&lds[C * 32768 + rb * 64 + sl];
    };
    auto LDB = [&](int j, int C, int NH, int KH) {
        int rb = NH * 128 + wc * 32 + (j & 1) * 16 + fr;
        int sl = ((KH * 4 + sg) ^ (rb & 7)) * 8;
        bh[j] = *(const f16x8*)&lds[C * 32768 + 16384 + rb * 64 + sl];
    };
    auto MM = [&](f32x4& d, int i, int j) {
        d = __builtin_amdgcn_mfma_f32_16x16x32_f16(ah[i], bh[j], d, 0, 0, 0);
    };
    auto STA = [&](int C, int H, int T) {
        int rg = Arow0 + H * 128 + w * 8 + (l >> 3);
        const u16* s = Ap + (size_t)rg * AST + (size_t)T * 64
                       + ((l & 7) ^ (rg & 7)) * 8;
        u16* d = &lds[C * 32768 + (H * 128 + w * 8) * 64];
        GLOAD16(s, d);
        GLOAD16(s + (size_t)64 * AST, d + 64 * 64);
    };
    auto STB = [&](int C, int H, int T) {
        int rg = Brow0 + H * 128 + w * 8 + (l >> 3);
        const u16* s = Bp + (size_t)rg * BST + (size_t)T * 64
                       + ((l & 7) ^ (rg & 7)) * 8;
        u16* d = &lds[C * 32768 + 16384 + (H * 128 + w * 8) * 64];
        GLOAD16(s, d);
        GLOAD16(s + (size_t)64 * BST, d + 64 * 64);
    };

    // prologue: tile0 all 4 halves (8 loads) + tile1 H0s (4 loads)
    STA(0, 0, 0); STA(0, 1, 0); STB(0, 0, 0); STB(0, 1, 0);
    STA(1, 0, 1); STB(1, 0, 1);
    VMW4                                       // tile0 landed; tile1-H0 in flight
    __builtin_amdgcn_s_barrier();

    for (int u = 0; u + 2 < nt; u += 2) {
        TILE8(0, STA(1,1,u+1), STB(1,1,u+1), STA(0,0,u+2), STB(0,0,u+2), VMW4)
        TILE8(1, STA(0,1,u+2), STB(0,1,u+2), STA(1,0,u+3), STB(1,0,u+3), VMW4)
    }
    // epilogue: tile nt-2 (stage nt-1 H1, drain), tile nt-1 (pure compute)
    TILE8(0, STA(1,1,nt-1), STB(1,1,nt-1), NOPS, NOPS, VMW0)
    TILE8(1, NOPS, NOPS, NOPS, NOPS, NOPS)
}

// ---------------------------------------------------------------------------
// P1: wT[n][h] = f16(64 * w[h][n]); rows 0-1023 = w_a, 1024-2047 = query
// ---------------------------------------------------------------------------
__global__ __launch_bounds__(256) void wprep_kernel(
    const float* __restrict__ wa, const float* __restrict__ qu,
    u16* __restrict__ wT)
{
    int idx = blockIdx.x * 256 + threadIdx.x;   // 0..1M-1
    int h = idx >> 10, n = idx & 1023;
    wT[(size_t)n * 1024 + h]          = f16_rne(wa[idx] * 64.0f);
    wT[(size_t)(1024 + n) * 1024 + h] = f16_rne(qu[idx] * 64.0f);
}

// ---------------------------------------------------------------------------
// P2: read x once -> x_f16 [b*2048+t][1024] (K1 A) + xT_f16 [b][h][t] (K4 B)
// ---------------------------------------------------------------------------
__global__ __launch_bounds__(256) void xprep_kernel(
    const float* __restrict__ x, u16* __restrict__ xT,
    u16* __restrict__ x_f16)
{
    __shared__ u16 tile[64][68];
    int b = blockIdx.z;
    int t0 = blockIdx.x * 64;
    int h0 = blockIdx.y * 64;
    const float* xb = x + ((size_t)b * NSEQ + t0) * NHID + h0;
    int tid = threadIdx.x;
    int tl = tid >> 4;               // 0..15
    int hl = (tid & 15) * 4;         // 0..60
    #pragma unroll
    for (int i = 0; i < 4; i++) {
        int r = i * 16 + tl;
        float4 v = *(const float4*)&xb[(size_t)r * NHID + hl];
        u16x4 hv;
        hv[0] = f16_rne(v.x); hv[1] = f16_rne(v.y);
        hv[2] = f16_rne(v.z); hv[3] = f16_rne(v.w);
        *(u16x4*)&tile[r][hl] = hv;
        *(u16x4*)&x_f16[((size_t)(b * NSEQ) + t0 + r) * NHID + h0 + hl] = hv;
    }
    __syncthreads();
    u16* xTb = xT + ((size_t)b * NHID + h0) * NSEQ + t0;
    int hl2 = tid >> 4;              // 0..15
    int tl2 = (tid & 15) * 4;        // 0..60
    #pragma unroll
    for (int i = 0; i < 4; i++) {
        int hh = i * 16 + hl2;
        u16x4 o;
        o[0] = tile[tl2 + 0][hh]; o[1] = tile[tl2 + 1][hh];
        o[2] = tile[tl2 + 2][hh]; o[3] = tile[tl2 + 3][hh];
        *(u16x4*)&xTb[(size_t)hh * NSEQ + tl2] = o;
    }
}

// ---------------------------------------------------------------------------
// K1: key = tanh(x @ w_a), q = x @ query   (plain f16, B pre-scaled by 64)
// ---------------------------------------------------------------------------
__global__ __launch_bounds__(512, 2) void k1_gemm(
    const u16* __restrict__ x_f16, const u16* __restrict__ wT,
    u16* __restrict__ k_f16, u16* __restrict__ q_f16)
{
    extern __shared__ u16 lds[];
    int wg = blockIdx.x;                       // 1024 blocks
    int nid = (wg & 7) * 128 + (wg >> 3);      // XCD-chunked
    int n0 = (nid & 7) * 256;
    int m0 = (nid >> 3) * 256;
    bool is_key = (n0 < 1024);

    f32x4 acc[2][2][4][2] = {};
    gemm_core64<1024, 1024>(x_f16, m0, wT, n0, 16, lds, acc);

    int tid = threadIdx.x;
    int l = tid & 63, w = tid >> 6;
    int wr = w >> 2, wc = w & 3;
    int fr = l & 15, fq = l >> 4;
    int nb = is_key ? n0 : (n0 - 1024);
    u16* outp = is_key ? k_f16 : q_f16;
    #pragma unroll
    for (int mh = 0; mh < 2; mh++)
    #pragma unroll
    for (int nh = 0; nh < 2; nh++)
    #pragma unroll
    for (int m = 0; m < 4; m++)
    #pragma unroll
    for (int n = 0; n < 2; n++)
    #pragma unroll
    for (int j = 0; j < 4; j++) {
        int grow = m0 + mh * 128 + wr * 64 + m * 16 + fq * 4 + j;
        int c    = nb + nh * 128 + wc * 32 + n * 16 + fr;
        float v = acc[mh][nh][m][n][j] * 0.015625f;   // /64 (B was scaled)
        outp[(size_t)grow * 1024 + c] = f16_rne(is_key ? fast_tanh(v) : v);
    }
}

// ---------------------------------------------------------------------------
// K2: logits = q . key  (causal 256x256 tiles) + upper-triangle zero-fill
// ---------------------------------------------------------------------------
__global__ __launch_bounds__(512, 2) void k2_logits(
    const u16* __restrict__ q_f16, const u16* __restrict__ k_f16,
    float* __restrict__ dmat)
{
    extern __shared__ u16 lds[];
    int wg = blockIdx.x;                       // 1024 = 576 compute + 448 zfill
    int tid = threadIdx.x;

    if (wg >= 576) {
        // zero-fill strictly-upper 256x256 tiles (tt > st)
        int z = wg - 576;                      // 0..447
        int b = z / 28;
        int lin = z - b * 28;
        int tt = 1;
        while ((tt + 1) * tt / 2 <= lin) tt++;
        int st = lin - tt * (tt - 1) / 2;      // st < tt
        float* db = dmat + (size_t)b * NSEQ * NSEQ;
        size_t base = (size_t)(st * 256) * NSEQ + tt * 256;
        float4 zz = make_float4(0.f, 0.f, 0.f, 0.f);
        #pragma unroll
        for (int i = 0; i < 32; i++) {
            int e = i * 512 + tid;
            int row = e >> 6, c4 = e & 63;
            *(float4*)&db[base + (size_t)row * NSEQ + c4 * 4] = zz;
        }
        return;
    }

    int nid = (wg & 7) * 72 + (wg >> 3);
    int b = nid / 36;
    int lin = nid - b * 36;
    int st = 0;
    while ((st + 1) * (st + 2) / 2 <= lin) st++;
    int tt = lin - st * (st + 1) / 2;
    int s0 = st * 256, t0 = tt * 256;
    int base = b * NSEQ;

    f32x4 acc[2][2][4][2] = {};
    gemm_core64<1024, 1024>(q_f16, base + s0, k_f16, base + t0, 16, lds, acc);

    float* db = dmat + (size_t)b * NSEQ * NSEQ;
    int l = tid & 63, w = tid >> 6;
    int wr = w >> 2, wc = w & 3;
    int fr = l & 15, fq = l >> 4;
    #pragma unroll
    for (int mh = 0; mh < 2; mh++)
    #pragma unroll
    for (int nh = 0; nh < 2; nh++)
    #pragma unroll
    for (int m = 0; m < 4; m++)
    #pragma unroll
    for (int n = 0; n < 2; n++)
    #pragma unroll
    for (int j = 0; j < 4; j++) {
        int s = s0 + mh * 128 + wr * 64 + m * 16 + fq * 4 + j;
        int t = t0 + nh * 128 + wc * 32 + n * 16 + fr;
        db[(size_t)s * NSEQ + t] = (t <= s) ? acc[mh][nh][m][n][j] : 0.0f;
    }
}

// ---------------------------------------------------------------------------
// K3: row-wise causal softmax; dmat writes only t0<=s (upper zeros from K2);
//     d_f16 band 256-aligned (K4's read range).
// ---------------------------------------------------------------------------
__global__ __launch_bounds__(256) void k3_softmax(
    float* __restrict__ dmat, u16* __restrict__ d_f16)
{
    __shared__ float redm[4];
    __shared__ float reds[4];
    int rowid = blockIdx.x;             // b*2048 + s
    int s = rowid & (NSEQ - 1);
    float* row = dmat + (size_t)rowid * NSEQ;
    int tid = threadIdx.x;
    int lane = tid & 63, w = tid >> 6;
    int t0 = tid * 8;

    float v[8];
    if (t0 <= s) {
        float4 a = *(const float4*)&row[t0];
        float4 c = *(const float4*)&row[t0 + 4];
        v[0] = a.x; v[1] = a.y; v[2] = a.z; v[3] = a.w;
        v[4] = c.x; v[5] = c.y; v[6] = c.z; v[7] = c.w;
        #pragma unroll
        for (int i = 0; i < 8; i++) if (t0 + i > s) v[i] = -INFINITY;
    } else {
        #pragma unroll
        for (int i = 0; i < 8; i++) v[i] = -INFINITY;
    }

    float m = -INFINITY;
    #pragma unroll
    for (int i = 0; i < 8; i++) m = fmaxf(m, v[i]);
    #pragma unroll
    for (int off = 32; off > 0; off >>= 1) m = fmaxf(m, __shfl_xor(m, off));
    if (lane == 0) redm[w] = m;
    __syncthreads();
    m = fmaxf(fmaxf(redm[0], redm[1]), fmaxf(redm[2], redm[3]));

    float sum = 0.f;
    float ev[8];
    #pragma unroll
    for (int i = 0; i < 8; i++) {
        ev[i] = (t0 + i <= s) ? __expf(v[i] - m) : 0.f;
        sum += ev[i];
    }
    #pragma unroll
    for (int off = 32; off > 0; off >>= 1) sum += __shfl_xor(sum, off);
    if (lane == 0) reds[w] = sum;
    __syncthreads();
    sum = reds[0] + reds[1] + reds[2] + reds[3];
    float inv = 1.0f / sum;

    float4 o0, o1;
    o0.x = ev[0] * inv; o0.y = ev[1] * inv; o0.z = ev[2] * inv; o0.w = ev[3] * inv;
    o1.x = ev[4] * inv; o1.y = ev[5] * inv; o1.z = ev[6] * inv; o1.w = ev[7] * inv;
    if (t0 <= s) {
        *(float4*)&row[t0] = o0;
        *(float4*)&row[t0 + 4] = o1;
    }
    if (t0 < (((s >> 8) + 1) << 8)) {
        u16x8 bv;
        bv[0] = f16_rne(o0.x); bv[1] = f16_rne(o0.y); bv[2] = f16_rne(o0.z); bv[3] = f16_rne(o0.w);
        bv[4] = f16_rne(o1.x); bv[5] = f16_rne(o1.y); bv[6] = f16_rne(o1.z); bv[7] = f16_rne(o1.w);
        *(u16x8*)&d_f16[(size_t)rowid * NSEQ + t0] = bv;
    }
}

// ---------------------------------------------------------------------------
// K4: a = d @ x  (256x256 8-phase core, K truncated at 256-aligned diagonal).
// LPT: heavy s-tiles first; ntile fastest; no XCD chunking (R8 lesson).
// ---------------------------------------------------------------------------
__global__ __launch_bounds__(512, 2) void k4_av(
    const u16* __restrict__ d_f16,
    const u16* __restrict__ xT,
    float* __restrict__ aout)
{
    extern __shared__ u16 lds[];
    int wg = blockIdx.x;                  // 512 = 8 st * 16 b * 4 nt
    int st = 7 - (wg >> 6);               // heavy first (st=7 -> nt=32)
    int rem = wg & 63;
    int b = rem >> 2;
    int ntile = rem & 3;
    int s0 = st * 256;
    int n0 = ntile * 256;
    int nt = 4 * (st + 1);                // covers t < 256*(st+1) = d_f16 band

    f32x4 acc[2][2][4][2] = {};
    gemm_core64<2048, 2048>(d_f16, b * 2048 + s0, xT, b * 1024 + n0, nt, lds, acc);

    float* ab = aout + (size_t)b * NSEQ * NHID;
    int tid = threadIdx.x;
    int l = tid & 63, w = tid >> 6;
    int wr = w >> 2, wc = w & 3;
    int fr = l & 15, fq = l >> 4;
    #pragma unroll
    for (int mh = 0; mh < 2; mh++)
    #pragma unroll
    for (int nh = 0; nh < 2; nh++)
    #pragma unroll
    for (int m = 0; m < 4; m++)
    #pragma unroll
    for (int n = 0; n < 2; n++)
    #pragma unroll
    for (int j = 0; j < 4; j++) {
        int s = s0 + mh * 128 + wr * 64 + m * 16 + fq * 4 + j;
        int c = n0 + nh * 128 + wc * 32 + n * 16 + fr;
        ab[(size_t)s * NHID + c] = acc[mh][nh][m][n][j];
    }
}

// ---------------------------------------------------------------------------
extern "C" void kernel_launch(void* const* d_in, const int* in_sizes, int n_in,
                              void* d_out, int out_size, void* d_ws, size_t ws_size,
                              hipStream_t stream)
{
    const float* x     = (const float*)d_in[0];
    const float* w_a   = (const float*)d_in[1];
    const float* query = (const float*)d_in[2];

    float* aout = (float*)d_out;                         // [16][2048][1024]
    float* dmat = aout + (size_t)NBATCH * NSEQ * NHID;   // [16][2048][2048]

    char* p = (char*)d_ws;
    u16* q_f16  = (u16*)p; p += (size_t)MALL * 1024 * 2;    // 64MB
    u16* x_f16  = (u16*)p; p += (size_t)MALL * 1024 * 2;    // 64MB (dead after K1)
    u16* k_f16  = (u16*)p; p += (size_t)MALL * 1024 * 2;    // 64MB (dead after K2)
    u16* d_f16  = x_f16;                                    // alias x_f16+k_f16 (128MB)
    u16* xT     = (u16*)p; p += (size_t)MALL * 1024 * 2;    // 64MB
    u16* wT     = (u16*)p; p += (size_t)2048 * 1024 * 2;    // 4MB
    (void)ws_size; (void)in_sizes; (void)n_in; (void)out_size;

    hipFuncSetAttribute((const void*)k1_gemm,
                        hipFuncAttributeMaxDynamicSharedMemorySize, 131072);
    hipFuncSetAttribute((const void*)k2_logits,
                        hipFuncAttributeMaxDynamicSharedMemorySize, 131072);
    hipFuncSetAttribute((const void*)k4_av,
                        hipFuncAttributeMaxDynamicSharedMemorySize, 131072);

    wprep_kernel<<<dim3(4096), 256, 0, stream>>>(w_a, query, wT);
    xprep_kernel<<<dim3(32, 16, 16), 256, 0, stream>>>(x, xT, x_f16);
    k1_gemm<<<dim3(1024), 512, 131072, stream>>>(x_f16, wT, k_f16, q_f16);
    k2_logits<<<dim3(1024), 512, 131072, stream>>>(q_f16, k_f16, dmat);
    k3_softmax<<<dim3(32768), 256, 0, stream>>>(dmat, d_f16);
    k4_av<<<dim3(512), 512, 131072, stream>>>(d_f16, xT, aout);
}